// Round 8
// baseline (452.038 us; speedup 1.0000x reference)
//
#include <hip/hip_runtime.h>

// Problem constants (B=2, S=1024, D=1024, H=16, hd=64, L=4, M=12)
#define BATCH 2
#define SEQ   1024
#define DIM   1024
#define NH    16
#define HD    64
#define NM    12
#define NTOK  (BATCH*SEQ)          // 2048
#define MEMROWS (BATCH*SEQ*NM)     // 24576
#define OUTT  2097152              // elements per output tensor
#define NEGBIG (-1.0e30f)

typedef __attribute__((ext_vector_type(8))) short short8;   // 8 bf16 (4 VGPRs)
typedef __attribute__((ext_vector_type(4))) float f32x4;    // MFMA C/D

__device__ __forceinline__ float bf2f(ushort u) {
    union { unsigned int i; float f; } t; t.i = ((unsigned int)u) << 16; return t.f;
}
__device__ __forceinline__ ushort f2bf(float f) {
    union { float f; unsigned int i; } t; t.f = f;
    unsigned int i = t.i;
    unsigned int lsb = (i >> 16) & 1u;
    i += 0x7fffu + lsb;
    return (ushort)(i >> 16);
}

// ---------------------------------------------------------------------------
// fp32 -> bf16 conversion for x, Wqkv, Wout (one pass, float4-vectorized)
// ---------------------------------------------------------------------------
__global__ __launch_bounds__(256) void cvt3_kernel(
    const float* __restrict__ a, ushort* __restrict__ ab, int na4,
    const float* __restrict__ b, ushort* __restrict__ bb, int nb4,
    const float* __restrict__ c, ushort* __restrict__ cb, int nc4)
{
    int i = blockIdx.x * 256 + threadIdx.x;
    if (i >= na4 + nb4 + nc4) return;
    const float* src; ushort* dst; int j;
    if (i < na4)            { src = a; dst = ab; j = i; }
    else if (i < na4 + nb4) { src = b; dst = bb; j = i - na4; }
    else                    { src = c; dst = cb; j = i - na4 - nb4; }
    float4 v = ((const float4*)src)[j];
    ushort4 o; o.x = f2bf(v.x); o.y = f2bf(v.y); o.z = f2bf(v.z); o.w = f2bf(v.w);
    ((ushort4*)dst)[j] = o;
}

// ---------------------------------------------------------------------------
// Wk transpose: WkT[c][kk] = Wk[kk][c]  (1024x1024 bf16, LDS 64x64 tiles).
// One-time ~3us cost; lets msc_direct load MFMA#1 B-frags straight from
// global, deleting 4.2M 8-way-conflicted scalar ds_writes (R6's 90us wall).
// ---------------------------------------------------------------------------
__global__ __launch_bounds__(256) void transpose_wk_kernel(
    const ushort* __restrict__ Wkb, ushort* __restrict__ WkT)
{
    __shared__ ushort tile[64][72];
    const int bx = (blockIdx.x & 15) * 64;   // src col block (c)
    const int by = (blockIdx.x >> 4) * 64;   // src row block (kk)
    const int tid = threadIdx.x;
    const int r = tid >> 2, c16 = (tid & 3) * 16;
    *(short8*)&tile[r][c16]     = *(const short8*)(Wkb + (size_t)(by + r) * 1024 + bx + c16);
    *(short8*)&tile[r][c16 + 8] = *(const short8*)(Wkb + (size_t)(by + r) * 1024 + bx + c16 + 8);
    __syncthreads();
    ushort tmp[16];
#pragma unroll
    for (int j = 0; j < 16; j++) tmp[j] = tile[c16 + j][r];
    ushort* dst = WkT + (size_t)(bx + r) * 1024 + by + c16;
    *(short8*)dst       = *(short8*)&tmp[0];
    *(short8*)(dst + 8) = *(short8*)&tmp[8];
}

// ---------------------------------------------------------------------------
// MFMA GEMM core conventions (verified):
//  A-frag: m=lane&15, k=qd*8+j ; B-frag: n=lane&15, k=qd*8+j
//  C/D:    col=lane&15, row=qd*4+reg
// ---------------------------------------------------------------------------

// ---------------------------------------------------------------------------
// FUSED qkv GEMM + LayerNorm(mem rows) — heterogeneous blocks.
// Blocks 0..383: qkv GEMM. Blocks 384..6527: LN of 4 mem rows each.
// (R4: 73.7us fused vs ~87us serial; ln's ~2.1TB/s access-pattern wall is
//  hidden under the GEMM's MFMA time.)
// ---------------------------------------------------------------------------
#define QKV_BLKS 384
__global__ __launch_bounds__(256) void qkv_ln_fused_kernel(
    const ushort* __restrict__ xb, const ushort* __restrict__ Wb,
    const float* __restrict__ bias, float* __restrict__ out,
    ushort* __restrict__ qkvb,
    const float* __restrict__ pq, const float* __restrict__ pk,
    const float* __restrict__ pv, ushort* __restrict__ mem_n)
{
    const int bid = blockIdx.x;
    const int tid = threadIdx.x;
    if (bid < QKV_BLKS) {
        // ---------------- qkv GEMM path ----------------
        __shared__ ushort As[128][40];
        __shared__ ushort Bs[128][40];
        const int w = tid >> 6, lane = tid & 63;
        const int n = lane & 15, qd = lane >> 4;
        const int wr = (w >> 1) * 64, wc = (w & 1) * 64;
        const int row0 = (bid / 24) * 128, col0 = (bid % 24) * 128;
        const int r1 = tid >> 2, o1 = (tid & 3) * 8;
        const int r2 = (tid + 256) >> 2, o2 = ((tid + 256) & 3) * 8;

        f32x4 acc[4][4];
#pragma unroll
        for (int mt = 0; mt < 4; mt++)
#pragma unroll
            for (int nt = 0; nt < 4; nt++) acc[mt][nt] = (f32x4){0.f, 0.f, 0.f, 0.f};

        for (int k0 = 0; k0 < 1024; k0 += 32) {
            *(short8*)&As[r1][o1] = *(const short8*)(xb + (size_t)(row0 + r1) * 1024 + k0 + o1);
            *(short8*)&As[r2][o2] = *(const short8*)(xb + (size_t)(row0 + r2) * 1024 + k0 + o2);
            *(short8*)&Bs[r1][o1] = *(const short8*)(Wb + (size_t)(col0 + r1) * 1024 + k0 + o1);
            *(short8*)&Bs[r2][o2] = *(const short8*)(Wb + (size_t)(col0 + r2) * 1024 + k0 + o2);
            __syncthreads();
            short8 af[4], bf[4];
#pragma unroll
            for (int mt = 0; mt < 4; mt++) af[mt] = *(const short8*)&As[wr + mt * 16 + n][qd * 8];
#pragma unroll
            for (int nt = 0; nt < 4; nt++) bf[nt] = *(const short8*)&Bs[wc + nt * 16 + n][qd * 8];
#pragma unroll
            for (int mt = 0; mt < 4; mt++)
#pragma unroll
                for (int nt = 0; nt < 4; nt++)
                    acc[mt][nt] = __builtin_amdgcn_mfma_f32_16x16x32_bf16(af[mt], bf[nt], acc[mt][nt], 0, 0, 0);
            __syncthreads();
        }
#pragma unroll
        for (int mt = 0; mt < 4; mt++)
#pragma unroll
            for (int nt = 0; nt < 4; nt++)
#pragma unroll
                for (int r = 0; r < 4; r++) {
                    int row = row0 + wr + mt * 16 + qd * 4 + r;
                    int col = col0 + wc + nt * 16 + n;
                    float val = acc[mt][nt][r] + bias[col];
                    int t = col >> 10, h = (col >> 6) & 15, d = col & 63;
                    int b = row >> 10, s = row & 1023;
                    size_t idx = (((size_t)(b * NH + h) * SEQ + s) * HD) + d;
                    size_t base = (t == 0) ? (size_t)3 * OUTT : (t == 1) ? (size_t)OUTT : (size_t)2 * OUTT;
                    out[base + idx] = val;
                    qkvb[(size_t)t * OUTT + idx] = f2bf(val);
                }
    } else {
        // ---------------- LayerNorm path (wave per row) ----------------
        const int wid = tid >> 6, lane = tid & 63;
        const int r = (bid - QKV_BLKS) * 4 + wid;   // mem row 0..24575
        const int idx = r % NM;
        const int bs = r / NM;
        const int s = bs & (SEQ - 1);
        const int b = bs >> 10;
        const int c = idx >> 2;                  // 0=q 1=k 2=v
        const int l = idx & 3;                   // layer
        const float* src = (c == 0) ? pq : ((c == 1) ? pk : pv);
        const size_t base = ((size_t)(l * BATCH + b) * NH) * (SEQ * HD) + (size_t)s * HD;

        float4 v4[4];
        float sum = 0.f, sumsq = 0.f;
#pragma unroll
        for (int p = 0; p < 4; p++) {
            int h = p * 4 + (lane >> 4);
            int d = (lane & 15) * 4;
            float4 v = *(const float4*)(src + base + (size_t)h * (SEQ * HD) + d);
            v4[p] = v;
            sum   += v.x + v.y + v.z + v.w;
            sumsq += v.x * v.x + v.y * v.y + v.z * v.z + v.w * v.w;
        }
#pragma unroll
        for (int off = 32; off > 0; off >>= 1) {
            sum   += __shfl_xor(sum, off);
            sumsq += __shfl_xor(sumsq, off);
        }
        float mu  = sum * (1.f / 1024.f);
        float var = fmaxf(sumsq * (1.f / 1024.f) - mu * mu, 0.f);
        float inv = rsqrtf(var + 1e-5f);
        ushort* dst = mem_n + (size_t)r * 1024;
#pragma unroll
        for (int p = 0; p < 4; p++) {
            int dp = (p * 64 + lane) * 4;
            ushort4 o;
            o.x = f2bf((v4[p].x - mu) * inv);
            o.y = f2bf((v4[p].y - mu) * inv);
            o.z = f2bf((v4[p].z - mu) * inv);
            o.w = f2bf((v4[p].w - mu) * inv);
            *(ushort4*)(dst + dp) = o;
        }
    }
}

// out GEMM: mergedb[2048x1024] x Woutb[1024x1024]^T + bout -> d_out fp32
__global__ __launch_bounds__(256) void mfma_out_kernel(
    const ushort* __restrict__ Ab, const ushort* __restrict__ Wb,
    const float* __restrict__ bias, float* __restrict__ C)
{
    __shared__ ushort As[128][40];
    __shared__ ushort Bs[128][40];
    const int tid = threadIdx.x;
    const int w = tid >> 6, lane = tid & 63;
    const int n = lane & 15, qd = lane >> 4;
    const int wr = (w >> 1) * 64, wc = (w & 1) * 64;
    const int row0 = blockIdx.y * 128, col0 = blockIdx.x * 128;
    const int r1 = tid >> 2, o1 = (tid & 3) * 8;
    const int r2 = (tid + 256) >> 2, o2 = ((tid + 256) & 3) * 8;

    f32x4 acc[4][4];
#pragma unroll
    for (int mt = 0; mt < 4; mt++)
#pragma unroll
        for (int nt = 0; nt < 4; nt++) acc[mt][nt] = (f32x4){0.f, 0.f, 0.f, 0.f};

    for (int k0 = 0; k0 < 1024; k0 += 32) {
        *(short8*)&As[r1][o1] = *(const short8*)(Ab + (size_t)(row0 + r1) * 1024 + k0 + o1);
        *(short8*)&As[r2][o2] = *(const short8*)(Ab + (size_t)(row0 + r2) * 1024 + k0 + o2);
        *(short8*)&Bs[r1][o1] = *(const short8*)(Wb + (size_t)(col0 + r1) * 1024 + k0 + o1);
        *(short8*)&Bs[r2][o2] = *(const short8*)(Wb + (size_t)(col0 + r2) * 1024 + k0 + o2);
        __syncthreads();
        short8 af[4], bf[4];
#pragma unroll
        for (int mt = 0; mt < 4; mt++) af[mt] = *(const short8*)&As[wr + mt * 16 + n][qd * 8];
#pragma unroll
        for (int nt = 0; nt < 4; nt++) bf[nt] = *(const short8*)&Bs[wc + nt * 16 + n][qd * 8];
#pragma unroll
        for (int mt = 0; mt < 4; mt++)
#pragma unroll
            for (int nt = 0; nt < 4; nt++)
                acc[mt][nt] = __builtin_amdgcn_mfma_f32_16x16x32_bf16(af[mt], bf[nt], acc[mt][nt], 0, 0, 0);
        __syncthreads();
    }
#pragma unroll
    for (int mt = 0; mt < 4; mt++)
#pragma unroll
        for (int nt = 0; nt < 4; nt++)
#pragma unroll
            for (int r = 0; r < 4; r++) {
                int row = row0 + wr + mt * 16 + qd * 4 + r;
                int col = col0 + wc + nt * 16 + n;
                C[(size_t)row * 1024 + col] = acc[mt][nt][r] + bias[col];
            }
}

// vproj per head: merged[t, h*64+d] += wvec_h[t,:]·Wv[h*64+d,:] + wsum*bv (in-place bf16)
__global__ __launch_bounds__(256) void mfma_vproj_kernel(
    const ushort* __restrict__ wvecb, const ushort* __restrict__ Wvb,
    const float* __restrict__ bv, const float* __restrict__ wmem,
    ushort* __restrict__ mergedb)
{
    __shared__ ushort As[128][40];
    __shared__ ushort Bs[64][40];
    const int tid = threadIdx.x;
    const int w = tid >> 6, lane = tid & 63;
    const int n = lane & 15, qd = lane >> 4;
    const int wr = (w >> 1) * 64, wc = (w & 1) * 32;
    const int row0 = blockIdx.x * 128;
    const int h = blockIdx.y;
    const int r1 = tid >> 2, o1 = (tid & 3) * 8;
    const int r2 = (tid + 256) >> 2, o2 = ((tid + 256) & 3) * 8;

    f32x4 acc[4][2];
#pragma unroll
    for (int mt = 0; mt < 4; mt++)
#pragma unroll
        for (int nt = 0; nt < 2; nt++) acc[mt][nt] = (f32x4){0.f, 0.f, 0.f, 0.f};

    for (int k0 = 0; k0 < 1024; k0 += 32) {
        *(short8*)&As[r1][o1] = *(const short8*)(wvecb + ((size_t)(row0 + r1) * NH + h) * 1024 + k0 + o1);
        *(short8*)&As[r2][o2] = *(const short8*)(wvecb + ((size_t)(row0 + r2) * NH + h) * 1024 + k0 + o2);
        *(short8*)&Bs[r1 & 63][o1] = *(const short8*)(Wvb + (size_t)(h * HD + (r1 & 63)) * 1024 + k0 + o1);
        __syncthreads();
        short8 af[4], bf[2];
#pragma unroll
        for (int mt = 0; mt < 4; mt++) af[mt] = *(const short8*)&As[wr + mt * 16 + n][qd * 8];
#pragma unroll
        for (int nt = 0; nt < 2; nt++) bf[nt] = *(const short8*)&Bs[wc + nt * 16 + n][qd * 8];
#pragma unroll
        for (int mt = 0; mt < 4; mt++)
#pragma unroll
            for (int nt = 0; nt < 2; nt++)
                acc[mt][nt] = __builtin_amdgcn_mfma_f32_16x16x32_bf16(af[mt], bf[nt], acc[mt][nt], 0, 0, 0);
        __syncthreads();
    }
#pragma unroll
    for (int mt = 0; mt < 4; mt++)
#pragma unroll
        for (int nt = 0; nt < 2; nt++)
#pragma unroll
            for (int r = 0; r < 4; r++) {
                int token = row0 + wr + mt * 16 + qd * 4 + r;
                int d = wc + nt * 16 + n;
                float ws = wmem[((size_t)token * NH + h) * 16 + 12];
                size_t mi = (size_t)token * DIM + h * HD + d;
                float val = bf2f(mergedb[mi]) + acc[mt][nt][r] + ws * bv[h * HD + d];
                mergedb[mi] = f2bf(val);
            }
}

// ---------------------------------------------------------------------------
// msc_direct v3: fused qproj+mem_scores, transpose-free.
// R6 post-mortem: v1/v2 both ~90us = LDS-scalar-write throughput wall
// (4.2M 8-way-conflicted ds_write_b16 from the in-kernel Wk transpose).
// v3: Wk^T precomputed once (transpose_wk_kernel); MFMA#1 B-frags load
// DIRECTLY from global WkT (L2-resident, 16B/lane). Only remaining LDS is
// the small conflict-free qpc handoff. MSC_T=4, K-split x2 -> grid 1024
// (4 blocks/CU, 16 waves/CU). Zero barriers (wave-private LDS only).
// ---------------------------------------------------------------------------
#define MSC_T 4
__global__ __launch_bounds__(256) void msc_direct_kernel(
    const ushort* __restrict__ qkvb, const ushort* __restrict__ mem_n,
    const ushort* __restrict__ WkT, const float* __restrict__ bqkv,
    float* __restrict__ msc0, float* __restrict__ msc1)
{
    __shared__ ushort qpc[4][MSC_T][4][72];  // per-wave qproj chunk 9.2 KB

    const int tid = threadIdx.x;
    const int w = tid >> 6, lane = tid & 63;
    const int n = lane & 15, qd = lane >> 4;
    const int t0 = blockIdx.x * MSC_T;
    const int kh = blockIdx.y;               // K-half

    // prologue: A-frags (q rows) for this wave's 4 heads, token = n&3
    short8 af0[4], af1[4];
    {
        const int g = t0 + (n & 3), b = g >> 10, s = g & 1023;
#pragma unroll
        for (int hh = 0; hh < 4; hh++) {
            const int h = w * 4 + hh;
            const ushort* qrow = qkvb + (((size_t)(b * NH + h) * SEQ + s) * HD);
            af0[hh] = *(const short8*)(qrow + qd * 8);
            af1[hh] = *(const short8*)(qrow + 32 + qd * 8);
        }
    }
    // qbk bias (kh==0 only): per-lane partial over k, reduce across qd groups
    float qbkv[4] = {0.f, 0.f, 0.f, 0.f};
    if (kh == 0) {
#pragma unroll
        for (int hh = 0; hh < 4; hh++) {
            const int h = w * 4 + hh;
            const float* bk = bqkv + DIM + h * HD;
            float s = 0.f;
#pragma unroll
            for (int j = 0; j < 8; j++) {
                s += bf2f((ushort)af0[hh][j]) * bk[qd * 8 + j];
                s += bf2f((ushort)af1[hh][j]) * bk[32 + qd * 8 + j];
            }
            s += __shfl_xor(s, 16);
            s += __shfl_xor(s, 32);
            qbkv[hh] = s;   // every lane holds qbk[token n&3][head w*4+hh]
        }
    }

    f32x4 acc[MSC_T];
#pragma unroll
    for (int t = 0; t < MSC_T; t++) acc[t] = (f32x4){0.f, 0.f, 0.f, 0.f};

    for (int ch = 0; ch < 8; ch++) {
        const int c0 = (kh * 8 + ch) * 64;
        // MFMA#1 per head: B-frag direct from WkT (global, L2-resident)
#pragma unroll
        for (int hh = 0; hh < 4; hh++) {
            const int h = w * 4 + hh;
#pragma unroll
            for (int nt = 0; nt < 4; nt++) {
                const ushort* wt = WkT + (size_t)(c0 + nt * 16 + n) * 1024 + h * HD;
                short8 bf0 = *(const short8*)(wt + qd * 8);
                short8 bf1 = *(const short8*)(wt + 32 + qd * 8);
                f32x4 z = (f32x4){0.f, 0.f, 0.f, 0.f};
                z = __builtin_amdgcn_mfma_f32_16x16x32_bf16(af0[hh], bf0, z, 0, 0, 0);
                z = __builtin_amdgcn_mfma_f32_16x16x32_bf16(af1[hh], bf1, z, 0, 0, 0);
                if (qd == 0) {   // rows 0..3 = tokens 0..3 (rest duplicates)
#pragma unroll
                    for (int r = 0; r < 4; r++)
                        qpc[w][r][hh][nt * 16 + n] = f2bf(z[r]);
                }
            }
        }
        // MFMA#2 per token (same-wave LDS RAW is in-order; no barrier):
        // rows = 4 heads (dup x4), cols = memories, B direct from global
#pragma unroll
        for (int t = 0; t < MSC_T; t++) {
            const int g = t0 + t;
            const int mrow = (n < NM) ? n : 0;
            const ushort* mb = mem_n + ((size_t)g * NM + mrow) * 1024 + c0;
            short8 a0 = *(const short8*)&qpc[w][t][n & 3][qd * 8];
            short8 a1 = *(const short8*)&qpc[w][t][n & 3][32 + qd * 8];
            short8 b0 = *(const short8*)(mb + qd * 8);
            short8 b1 = *(const short8*)(mb + 32 + qd * 8);
            acc[t] = __builtin_amdgcn_mfma_f32_16x16x32_bf16(a0, b0, acc[t], 0, 0, 0);
            acc[t] = __builtin_amdgcn_mfma_f32_16x16x32_bf16(a1, b1, acc[t], 0, 0, 0);
        }
    }
    // epilogue: qd==0 rows carry heads 0..3
#pragma unroll
    for (int t = 0; t < MSC_T; t++) {
        const size_t g = t0 + t;
#pragma unroll
        for (int r = 0; r < 4; r++) {
            float qb = __shfl(qbkv[r], t);   // all lanes execute; source lane t
            if (qd == 0 && n < NM) {
                const int h = w * 4 + r;
                if (kh == 0)
                    msc0[(g * NH + h) * NM + n] = 0.125f * (acc[t][r] + qb);
                else
                    msc1[(g * NH + h) * NM + n] = 0.125f * acc[t][r];
            }
        }
    }
}

// ---------------------------------------------------------------------------
// Flash attention (MFMA bf16), 8-wave split-KV. msc = msc0 + msc1 (K-halves).
// ---------------------------------------------------------------------------
#define TQ 64
#define TK 64
__global__ __launch_bounds__(512) void flash_attn_kernel(
    const ushort* __restrict__ qkvb, const float* __restrict__ msc0,
    const float* __restrict__ msc1,
    ushort* __restrict__ mergedb, float* __restrict__ wmem)
{
    // 55296 B total: Ks[2][64][72] | Vt[2][64][72] | Ps[8][16][72]
    // cbuf (combine, 4x64x25 f32 = 25600 B) aliases Ks/Vt after the KV loop.
    __shared__ __align__(16) char smem[55296];
    ushort (*Ks)[TK][72]  = (ushort (*)[TK][72])smem;
    ushort (*Vt)[HD][72]  = (ushort (*)[HD][72])(smem + 18432);
    ushort (*Ps)[16][72]  = (ushort (*)[16][72])(smem + 36864);
    float  (*cbuf)[64][25] = (float (*)[64][25])smem;

    const int bxr = blockIdx.x;
    const int qt = (bxr & 1) ? (bxr >> 1) : (15 - (bxr >> 1));
    const int bh = blockIdx.y;
    const int b = bh >> 4, h = bh & 15;
    const int tid = threadIdx.x;
    const int w = tid >> 6;        // 0..7
    const int g = w >> 2;          // kv parity group
    const int wq = w & 3;          // q sub-tile within the 64-row block
    const int lane = tid & 63;
    const int n = lane & 15;
    const int qd = lane >> 4;

    const ushort* qb = qkvb;
    const ushort* kb = qkvb + (size_t)OUTT;
    const ushort* vb = qkvb + (size_t)2 * OUTT;
    const size_t headoff = (size_t)bh * SEQ * HD;

    const int qrow0 = qt * TQ + wq * 16;
    const ushort* qp = qb + headoff + (size_t)(qrow0 + n) * HD;
    short8 qf0 = *(const short8*)(qp + qd * 8);
    short8 qf1 = *(const short8*)(qp + 32 + qd * 8);

    float mrow[4], lrow[4];
    f32x4 Oacc[4];
#pragma unroll
    for (int r = 0; r < 4; r++) { mrow[r] = NEGBIG; lrow[r] = 0.f; }
#pragma unroll
    for (int nt = 0; nt < 4; nt++) Oacc[nt] = (f32x4){0.f, 0.f, 0.f, 0.f};

    // staging indices within each 256-thread group
    const int gtid = tid & 255;
    const int key = gtid >> 2;
    const int c0 = (gtid & 3) * 16;
    const int nsteps = (qt + 2) >> 1;   // ceil((qt+1)/2)

    for (int step = 0; step < nsteps; ++step) {
        const int kt = 2 * step + g;
        const bool act = (kt <= qt);
        if (act) {
            const ushort* kg = kb + headoff + (size_t)(kt * TK + key) * HD + c0;
            *(short8*)&Ks[g][key][c0]     = *(const short8*)kg;
            *(short8*)&Ks[g][key][c0 + 8] = *(const short8*)(kg + 8);
            const ushort* vg = vb + headoff + (size_t)(kt * TK + key) * HD + c0;
            ushort vs[16];
            *(short8*)&vs[0] = *(const short8*)vg;
            *(short8*)&vs[8] = *(const short8*)(vg + 8);
#pragma unroll
            for (int i = 0; i < 16; i++) Vt[g][c0 + i][key] = vs[i];
        }
        __syncthreads();
        if (act) {
            f32x4 sacc[4];
#pragma unroll
            for (int kc = 0; kc < 4; kc++) {
                short8 kf0 = *(const short8*)&Ks[g][kc * 16 + n][qd * 8];
                short8 kf1 = *(const short8*)&Ks[g][kc * 16 + n][32 + qd * 8];
                f32x4 z = (f32x4){0.f, 0.f, 0.f, 0.f};
                z = __builtin_amdgcn_mfma_f32_16x16x32_bf16(qf0, kf0, z, 0, 0, 0);
                z = __builtin_amdgcn_mfma_f32_16x16x32_bf16(qf1, kf1, z, 0, 0, 0);
                sacc[kc] = z;
            }
            const bool diag = (kt == qt);
#pragma unroll
            for (int kc = 0; kc < 4; kc++) {
#pragma unroll
                for (int r = 0; r < 4; r++) {
                    float sv = sacc[kc][r] * 0.125f;
                    if (diag) {
                        int qrow = qrow0 + qd * 4 + r;
                        int kk = kt * TK + kc * 16 + n;
                        if (kk > qrow) sv = NEGBIG;
                    }
                    sacc[kc][r] = sv;
                }
            }
            float alpha[4];
#pragma unroll
            for (int r = 0; r < 4; r++) {
                float mx = fmaxf(fmaxf(sacc[0][r], sacc[1][r]), fmaxf(sacc[2][r], sacc[3][r]));
                mx = fmaxf(mx, __shfl_xor(mx, 1));
                mx = fmaxf(mx, __shfl_xor(mx, 2));
                mx = fmaxf(mx, __shfl_xor(mx, 4));
                mx = fmaxf(mx, __shfl_xor(mx, 8));
                float mnew = fmaxf(mrow[r], mx);
                alpha[r] = __expf(mrow[r] - mnew);
                mrow[r] = mnew;
            }
            float psum[4] = {0.f, 0.f, 0.f, 0.f};
#pragma unroll
            for (int kc = 0; kc < 4; kc++) {
#pragma unroll
                for (int r = 0; r < 4; r++) {
                    float p = __expf(sacc[kc][r] - mrow[r]);
                    psum[r] += p;
                    Ps[w][qd * 4 + r][kc * 16 + n] = f2bf(p);
                }
            }
#pragma unroll
            for (int r = 0; r < 4; r++) {
                float ps = psum[r];
                ps += __shfl_xor(ps, 1);
                ps += __shfl_xor(ps, 2);
                ps += __shfl_xor(ps, 4);
                ps += __shfl_xor(ps, 8);
                lrow[r] = alpha[r] * lrow[r] + ps;
            }
#pragma unroll
            for (int nt = 0; nt < 4; nt++)
#pragma unroll
                for (int r = 0; r < 4; r++)
                    Oacc[nt][r] *= alpha[r];
            short8 pf0 = *(const short8*)&Ps[w][n][qd * 8];
            short8 pf1 = *(const short8*)&Ps[w][n][32 + qd * 8];
#pragma unroll
            for (int nt = 0; nt < 4; nt++) {
                short8 vf0 = *(const short8*)&Vt[g][nt * 16 + n][qd * 8];
                short8 vf1 = *(const short8*)&Vt[g][nt * 16 + n][32 + qd * 8];
                f32x4 z = Oacc[nt];
                z = __builtin_amdgcn_mfma_f32_16x16x32_bf16(pf0, vf0, z, 0, 0, 0);
                z = __builtin_amdgcn_mfma_f32_16x16x32_bf16(pf1, vf1, z, 0, 0, 0);
                Oacc[nt] = z;
            }
        }
        __syncthreads();
    }

    // --- two-way combine: group 1 hands its state to group 0 via LDS ---
    if (g == 1) {
        float* cb = cbuf[wq][lane];
#pragma unroll
        for (int nt = 0; nt < 4; nt++)
#pragma unroll
            for (int r = 0; r < 4; r++) cb[nt * 4 + r] = Oacc[nt][r];
#pragma unroll
        for (int r = 0; r < 4; r++) { cb[16 + r] = mrow[r]; cb[20 + r] = lrow[r]; }
    }
    __syncthreads();
    if (g == 1) return;

    {
        const float* cb = cbuf[wq][lane];
#pragma unroll
        for (int r = 0; r < 4; r++) {
            float m1 = cb[16 + r], l1 = cb[20 + r];
            float mnew = fmaxf(mrow[r], m1);
            float a0 = __expf(mrow[r] - mnew);
            float a1 = __expf(m1 - mnew);
            lrow[r] = a0 * lrow[r] + a1 * l1;
#pragma unroll
            for (int nt = 0; nt < 4; nt++)
                Oacc[nt][r] = a0 * Oacc[nt][r] + a1 * cb[nt * 4 + r];
            mrow[r] = mnew;
        }
    }

#pragma unroll
    for (int r = 0; r < 4; r++) {
        int srow = qrow0 + qd * 4 + r;
        const size_t midx = ((size_t)(b * SEQ + srow) * NH + h) * NM;
        float mpv[NM];
#pragma unroll
        for (int j = 0; j < NM; j++) mpv[j] = msc0[midx + j] + msc1[midx + j];
        float mm = NEGBIG;
#pragma unroll
        for (int j = 0; j < NM; j++) mm = fmaxf(mm, mpv[j]);
        float mf = fmaxf(mrow[r], mm);
        float al = __expf(mrow[r] - mf);
        float msum = 0.f;
#pragma unroll
        for (int j = 0; j < NM; j++) msum += __expf(mpv[j] - mf);
        float lf = al * lrow[r] + msum;
        float inv = 1.f / lf;
        float scale = al * inv;
        ushort* mrow_out = mergedb + (size_t)(b * SEQ + srow) * DIM + h * HD;
#pragma unroll
        for (int nt = 0; nt < 4; nt++)
            mrow_out[nt * 16 + n] = f2bf(Oacc[nt][r] * scale);
        size_t wb = ((size_t)(b * SEQ + srow) * NH + h) * 16;
        if (n < 12)       wmem[wb + n]  = __expf(mpv[n] - mf) * inv;
        else if (n == 12) wmem[wb + 12] = msum * inv;
    }
}

// ---------------------------------------------------------------------------
// wvec[bs,h,:] = sum_m wmem[bs,h,m] * mem_n[bs,m,:]  (bf16 out)
// ---------------------------------------------------------------------------
__global__ __launch_bounds__(256) void wvec_kernel(
    const float* __restrict__ wmem, const ushort* __restrict__ mem_n,
    ushort* __restrict__ wvecb)
{
    __shared__ ushort memL[NM][1032];
    __shared__ float wL[NH][NM];
    const int bs = blockIdx.x;
    const int tid = threadIdx.x;

    for (int t = tid; t < NM * 256; t += 256) {
        int m = t >> 8, c4 = (t & 255) << 2;
        *(ushort4*)&memL[m][c4] = *(const ushort4*)(mem_n + ((size_t)bs * NM + m) * 1024 + c4);
    }
    if (tid < NH * NM) {
        int h = tid / NM, m = tid % NM;
        wL[h][m] = wmem[((size_t)bs * NH + h) * 16 + m];
    }
    __syncthreads();

    for (int h = 0; h < NH; h++) {
#pragma unroll
        for (int c0 = 0; c0 < 1024; c0 += 256) {
            int c = c0 + tid;
            float acc = 0.f;
#pragma unroll
            for (int m = 0; m < NM; m++)
                acc = fmaf(wL[h][m], bf2f(memL[m][c]), acc);
            wvecb[((size_t)bs * NH + h) * 1024 + c] = f2bf(acc);
        }
    }
}

// ---------------------------------------------------------------------------
extern "C" void kernel_launch(void* const* d_in, const int* in_sizes, int n_in,
                              void* d_out, int out_size, void* d_ws, size_t ws_size,
                              hipStream_t stream) {
    const float* x    = (const float*)d_in[0];
    const float* pk   = (const float*)d_in[1];
    const float* pv   = (const float*)d_in[2];
    const float* pq   = (const float*)d_in[3];
    const float* Wqkv = (const float*)d_in[4];
    const float* bqkv = (const float*)d_in[5];
    const float* Wout = (const float*)d_in[6];
    const float* bout = (const float*)d_in[7];
    float* out = (float*)d_out;

    // ws: mem_n 50.3 | wvecb 67.1 | msc 1.6 | wmem 2.1 |
    //     qkvb 12.6 | Wqkvb 6.3 | Woutb 2.1 | xb/mergedb 4.2 (aliased) |
    //     WkT 2.1  ~148 MB
    ushort* mem_n  = (ushort*)d_ws;
    ushort* wvecb  = mem_n + (size_t)MEMROWS * 1024;
    float*  msc    = (float*)(wvecb + (size_t)NTOK * NH * 1024);
    float*  wmem   = msc + (size_t)NTOK * NH * NM;
    ushort* qkvb   = (ushort*)(wmem + (size_t)NTOK * NH * 16);
    ushort* Wqkvb  = qkvb + (size_t)3 * OUTT;
    ushort* Woutb  = Wqkvb + (size_t)3072 * 1024;
    ushort* xb     = Woutb + (size_t)1024 * 1024;
    ushort* mergedb = xb;                                   // alias: xb dead after qkv gemm
    ushort* WkT    = xb + (size_t)NTOK * 1024;              // 2 MB, after xb region
    // msc2 (K-half-1 partials, 1.5 MB) aliases wvecb: msc2 dead before
    // wvec_kernel writes wvecb (flash reads it in between, both pre-wvec).
    float*  msc2   = (float*)wvecb;

    const int na4 = NTOK * DIM / 4, nb4 = 3 * DIM * DIM / 4, nc4 = DIM * DIM / 4;

    // 1. bf16 conversions
    cvt3_kernel<<<(na4 + nb4 + nc4 + 255) / 256, 256, 0, stream>>>(
        x, xb, na4, Wqkv, Wqkvb, nb4, Wout, Woutb, nc4);
    // 1b. Wk transpose (one-time, ~3us) -> WkT for msc_direct
    transpose_wk_kernel<<<256, 256, 0, stream>>>(Wqkvb + (size_t)DIM * DIM, WkT);
    // 2+3. FUSED: qkv GEMM (384 blocks) + layernorm of mem rows (6144 blocks).
    qkv_ln_fused_kernel<<<QKV_BLKS + MEMROWS / 4, 256, 0, stream>>>(
        xb, Wqkvb, bqkv, out, qkvb, pq, pk, pv, mem_n);
    // 4+5. FUSED mem scores v3: transpose-free, barrier-free, K-split x2.
    msc_direct_kernel<<<dim3(NTOK / MSC_T, 2), 256, 0, stream>>>(
        qkvb, mem_n, WkT, bqkv, msc, msc2);
    // 6. flash attention (8-wave split-KV) -> mergedb bf16, wmem
    flash_attn_kernel<<<dim3(16, 32), 512, 0, stream>>>(qkvb, msc, msc2, mergedb, wmem);
    // 7. wvec
    wvec_kernel<<<NTOK, 256, 0, stream>>>(wmem, mem_n, wvecb);
    // 8. vproj (MFMA, per head): mergedb += wvec@Wv^T + wsum*bv (in place)
    mfma_vproj_kernel<<<dim3(16, NH), 256, 0, stream>>>(
        wvecb, Wqkvb + (size_t)2 * DIM * DIM, bqkv + 2 * DIM, wmem, mergedb);
    // 9. out GEMM (MFMA) -> d_out fp32
    mfma_out_kernel<<<dim3(8, 16), 256, 0, stream>>>(mergedb, Woutb, bout, out);
}

// Round 9
// 362.616 us; speedup vs baseline: 1.2466x; 1.2466x over previous
//
#include <hip/hip_runtime.h>

// Problem constants (B=2, S=1024, D=1024, H=16, hd=64, L=4, M=12)
#define BATCH 2
#define SEQ   1024
#define DIM   1024
#define NH    16
#define HD    64
#define NM    12
#define NTOK  (BATCH*SEQ)          // 2048
#define MEMROWS (BATCH*SEQ*NM)     // 24576
#define OUTT  2097152              // elements per output tensor
#define NEGBIG (-1.0e30f)

typedef __attribute__((ext_vector_type(8))) short short8;   // 8 bf16 (4 VGPRs)
typedef __attribute__((ext_vector_type(4))) float f32x4;    // MFMA C/D

__device__ __forceinline__ float bf2f(ushort u) {
    union { unsigned int i; float f; } t; t.i = ((unsigned int)u) << 16; return t.f;
}
__device__ __forceinline__ ushort f2bf(float f) {
    union { float f; unsigned int i; } t; t.f = f;
    unsigned int i = t.i;
    unsigned int lsb = (i >> 16) & 1u;
    i += 0x7fffu + lsb;
    return (ushort)(i >> 16);
}

// ---------------------------------------------------------------------------
// fp32 -> bf16 conversion for x, Wqkv, Wout (one pass, float4-vectorized)
// ---------------------------------------------------------------------------
__global__ __launch_bounds__(256) void cvt3_kernel(
    const float* __restrict__ a, ushort* __restrict__ ab, int na4,
    const float* __restrict__ b, ushort* __restrict__ bb, int nb4,
    const float* __restrict__ c, ushort* __restrict__ cb, int nc4)
{
    int i = blockIdx.x * 256 + threadIdx.x;
    if (i >= na4 + nb4 + nc4) return;
    const float* src; ushort* dst; int j;
    if (i < na4)            { src = a; dst = ab; j = i; }
    else if (i < na4 + nb4) { src = b; dst = bb; j = i - na4; }
    else                    { src = c; dst = cb; j = i - na4 - nb4; }
    float4 v = ((const float4*)src)[j];
    ushort4 o; o.x = f2bf(v.x); o.y = f2bf(v.y); o.z = f2bf(v.z); o.w = f2bf(v.w);
    ((ushort4*)dst)[j] = o;
}

// ---------------------------------------------------------------------------
// Wk transpose: WkT[c][kk] = Wk[kk][c]  (1024x1024 bf16, LDS 64x64 tiles).
// One-time ~3us; validated end-to-end in R8. Lets mfma_qproj stage its
// B-tile with vectorized 16B LDS writes instead of 16 scalar 16-way-
// conflicted ds_writes per thread (R6 diagnosis).
// ---------------------------------------------------------------------------
__global__ __launch_bounds__(256) void transpose_wk_kernel(
    const ushort* __restrict__ Wkb, ushort* __restrict__ WkT)
{
    __shared__ ushort tile[64][72];
    const int bx = (blockIdx.x & 15) * 64;   // src col block (c)
    const int by = (blockIdx.x >> 4) * 64;   // src row block (kk)
    const int tid = threadIdx.x;
    const int r = tid >> 2, c16 = (tid & 3) * 16;
    *(short8*)&tile[r][c16]     = *(const short8*)(Wkb + (size_t)(by + r) * 1024 + bx + c16);
    *(short8*)&tile[r][c16 + 8] = *(const short8*)(Wkb + (size_t)(by + r) * 1024 + bx + c16 + 8);
    __syncthreads();
    ushort tmp[16];
#pragma unroll
    for (int j = 0; j < 16; j++) tmp[j] = tile[c16 + j][r];
    ushort* dst = WkT + (size_t)(bx + r) * 1024 + by + c16;
    *(short8*)dst       = *(short8*)&tmp[0];
    *(short8*)(dst + 8) = *(short8*)&tmp[8];
}

// ---------------------------------------------------------------------------
// MFMA GEMM core conventions (verified):
//  A-frag: m=lane&15, k=qd*8+j ; B-frag: n=lane&15, k=qd*8+j
//  C/D:    col=lane&15, row=qd*4+reg
// LDS tiles padded to 40 elems/row (80 B, 16B-aligned).
// ---------------------------------------------------------------------------

// ---------------------------------------------------------------------------
// FUSED qkv GEMM + LayerNorm(mem rows) — heterogeneous blocks.
// Blocks 0..383: qkv GEMM. Blocks 384..6527: LN of 4 mem rows each.
// (R4: 73.7us fused vs ~87us serial; ln's ~2.1TB/s access-pattern wall is
//  hidden under the GEMM's MFMA time.)
// ---------------------------------------------------------------------------
#define QKV_BLKS 384
__global__ __launch_bounds__(256) void qkv_ln_fused_kernel(
    const ushort* __restrict__ xb, const ushort* __restrict__ Wb,
    const float* __restrict__ bias, float* __restrict__ out,
    ushort* __restrict__ qkvb,
    const float* __restrict__ pq, const float* __restrict__ pk,
    const float* __restrict__ pv, ushort* __restrict__ mem_n)
{
    const int bid = blockIdx.x;
    const int tid = threadIdx.x;
    if (bid < QKV_BLKS) {
        // ---------------- qkv GEMM path ----------------
        __shared__ ushort As[128][40];
        __shared__ ushort Bs[128][40];
        const int w = tid >> 6, lane = tid & 63;
        const int n = lane & 15, qd = lane >> 4;
        const int wr = (w >> 1) * 64, wc = (w & 1) * 64;
        const int row0 = (bid / 24) * 128, col0 = (bid % 24) * 128;
        const int r1 = tid >> 2, o1 = (tid & 3) * 8;
        const int r2 = (tid + 256) >> 2, o2 = ((tid + 256) & 3) * 8;

        f32x4 acc[4][4];
#pragma unroll
        for (int mt = 0; mt < 4; mt++)
#pragma unroll
            for (int nt = 0; nt < 4; nt++) acc[mt][nt] = (f32x4){0.f, 0.f, 0.f, 0.f};

        for (int k0 = 0; k0 < 1024; k0 += 32) {
            *(short8*)&As[r1][o1] = *(const short8*)(xb + (size_t)(row0 + r1) * 1024 + k0 + o1);
            *(short8*)&As[r2][o2] = *(const short8*)(xb + (size_t)(row0 + r2) * 1024 + k0 + o2);
            *(short8*)&Bs[r1][o1] = *(const short8*)(Wb + (size_t)(col0 + r1) * 1024 + k0 + o1);
            *(short8*)&Bs[r2][o2] = *(const short8*)(Wb + (size_t)(col0 + r2) * 1024 + k0 + o2);
            __syncthreads();
            short8 af[4], bf[4];
#pragma unroll
            for (int mt = 0; mt < 4; mt++) af[mt] = *(const short8*)&As[wr + mt * 16 + n][qd * 8];
#pragma unroll
            for (int nt = 0; nt < 4; nt++) bf[nt] = *(const short8*)&Bs[wc + nt * 16 + n][qd * 8];
#pragma unroll
            for (int mt = 0; mt < 4; mt++)
#pragma unroll
                for (int nt = 0; nt < 4; nt++)
                    acc[mt][nt] = __builtin_amdgcn_mfma_f32_16x16x32_bf16(af[mt], bf[nt], acc[mt][nt], 0, 0, 0);
            __syncthreads();
        }
#pragma unroll
        for (int mt = 0; mt < 4; mt++)
#pragma unroll
            for (int nt = 0; nt < 4; nt++)
#pragma unroll
                for (int r = 0; r < 4; r++) {
                    int row = row0 + wr + mt * 16 + qd * 4 + r;
                    int col = col0 + wc + nt * 16 + n;
                    float val = acc[mt][nt][r] + bias[col];
                    int t = col >> 10, h = (col >> 6) & 15, d = col & 63;
                    int b = row >> 10, s = row & 1023;
                    size_t idx = (((size_t)(b * NH + h) * SEQ + s) * HD) + d;
                    size_t base = (t == 0) ? (size_t)3 * OUTT : (t == 1) ? (size_t)OUTT : (size_t)2 * OUTT;
                    out[base + idx] = val;
                    qkvb[(size_t)t * OUTT + idx] = f2bf(val);
                }
    } else {
        // ---------------- LayerNorm path (wave per row) ----------------
        const int wid = tid >> 6, lane = tid & 63;
        const int r = (bid - QKV_BLKS) * 4 + wid;   // mem row 0..24575
        const int idx = r % NM;
        const int bs = r / NM;
        const int s = bs & (SEQ - 1);
        const int b = bs >> 10;
        const int c = idx >> 2;                  // 0=q 1=k 2=v
        const int l = idx & 3;                   // layer
        const float* src = (c == 0) ? pq : ((c == 1) ? pk : pv);
        const size_t base = ((size_t)(l * BATCH + b) * NH) * (SEQ * HD) + (size_t)s * HD;

        float4 v4[4];
        float sum = 0.f, sumsq = 0.f;
#pragma unroll
        for (int p = 0; p < 4; p++) {
            int h = p * 4 + (lane >> 4);
            int d = (lane & 15) * 4;
            float4 v = *(const float4*)(src + base + (size_t)h * (SEQ * HD) + d);
            v4[p] = v;
            sum   += v.x + v.y + v.z + v.w;
            sumsq += v.x * v.x + v.y * v.y + v.z * v.z + v.w * v.w;
        }
#pragma unroll
        for (int off = 32; off > 0; off >>= 1) {
            sum   += __shfl_xor(sum, off);
            sumsq += __shfl_xor(sumsq, off);
        }
        float mu  = sum * (1.f / 1024.f);
        float var = fmaxf(sumsq * (1.f / 1024.f) - mu * mu, 0.f);
        float inv = rsqrtf(var + 1e-5f);
        ushort* dst = mem_n + (size_t)r * 1024;
#pragma unroll
        for (int p = 0; p < 4; p++) {
            int dp = (p * 64 + lane) * 4;
            ushort4 o;
            o.x = f2bf((v4[p].x - mu) * inv);
            o.y = f2bf((v4[p].y - mu) * inv);
            o.z = f2bf((v4[p].z - mu) * inv);
            o.w = f2bf((v4[p].w - mu) * inv);
            *(ushort4*)(dst + dp) = o;
        }
    }
}

// out GEMM: mergedb[2048x1024] x Woutb[1024x1024]^T + bout -> d_out fp32
__global__ __launch_bounds__(256) void mfma_out_kernel(
    const ushort* __restrict__ Ab, const ushort* __restrict__ Wb,
    const float* __restrict__ bias, float* __restrict__ C)
{
    __shared__ ushort As[128][40];
    __shared__ ushort Bs[128][40];
    const int tid = threadIdx.x;
    const int w = tid >> 6, lane = tid & 63;
    const int n = lane & 15, qd = lane >> 4;
    const int wr = (w >> 1) * 64, wc = (w & 1) * 64;
    const int row0 = blockIdx.y * 128, col0 = blockIdx.x * 128;
    const int r1 = tid >> 2, o1 = (tid & 3) * 8;
    const int r2 = (tid + 256) >> 2, o2 = ((tid + 256) & 3) * 8;

    f32x4 acc[4][4];
#pragma unroll
    for (int mt = 0; mt < 4; mt++)
#pragma unroll
        for (int nt = 0; nt < 4; nt++) acc[mt][nt] = (f32x4){0.f, 0.f, 0.f, 0.f};

    for (int k0 = 0; k0 < 1024; k0 += 32) {
        *(short8*)&As[r1][o1] = *(const short8*)(Ab + (size_t)(row0 + r1) * 1024 + k0 + o1);
        *(short8*)&As[r2][o2] = *(const short8*)(Ab + (size_t)(row0 + r2) * 1024 + k0 + o2);
        *(short8*)&Bs[r1][o1] = *(const short8*)(Wb + (size_t)(col0 + r1) * 1024 + k0 + o1);
        *(short8*)&Bs[r2][o2] = *(const short8*)(Wb + (size_t)(col0 + r2) * 1024 + k0 + o2);
        __syncthreads();
        short8 af[4], bf[4];
#pragma unroll
        for (int mt = 0; mt < 4; mt++) af[mt] = *(const short8*)&As[wr + mt * 16 + n][qd * 8];
#pragma unroll
        for (int nt = 0; nt < 4; nt++) bf[nt] = *(const short8*)&Bs[wc + nt * 16 + n][qd * 8];
#pragma unroll
        for (int mt = 0; mt < 4; mt++)
#pragma unroll
            for (int nt = 0; nt < 4; nt++)
                acc[mt][nt] = __builtin_amdgcn_mfma_f32_16x16x32_bf16(af[mt], bf[nt], acc[mt][nt], 0, 0, 0);
        __syncthreads();
    }
#pragma unroll
    for (int mt = 0; mt < 4; mt++)
#pragma unroll
        for (int nt = 0; nt < 4; nt++)
#pragma unroll
            for (int r = 0; r < 4; r++) {
                int row = row0 + wr + mt * 16 + qd * 4 + r;
                int col = col0 + wc + nt * 16 + n;
                C[(size_t)row * 1024 + col] = acc[mt][nt][r] + bias[col];
            }
}

// qproj per head: q_h[2048x64] @ WkBlock_h[64x1024] -> qproj bf16.
// B-tile staged from precomputed WkT with vectorized 16B LDS writes
// (replaces R5's 16 scalar 16-way-conflicted ds_writes per thread).
__global__ __launch_bounds__(256) void mfma_qproj_kernel(
    const ushort* __restrict__ qkvb, const ushort* __restrict__ WkT,
    ushort* __restrict__ qproj)
{
    __shared__ ushort As[128][40];
    __shared__ ushort Bs[128][40];
    const int tid = threadIdx.x;
    const int w = tid >> 6, lane = tid & 63;
    const int n = lane & 15, qd = lane >> 4;
    const int wr = (w >> 1) * 64, wc = (w & 1) * 64;
    const int row0 = blockIdx.y * 128, col0 = blockIdx.x * 128;
    const int h = blockIdx.z;
    const int b = row0 >> 10, s0 = row0 & 1023;
    const ushort* Abase = qkvb + ((size_t)(b * NH + h) * SEQ + s0) * HD;
    const int r1 = tid >> 2, o1 = (tid & 3) * 8;
    const int r2 = (tid + 256) >> 2, o2 = ((tid + 256) & 3) * 8;
    const int r1b = tid >> 1, o1b = (tid & 1) * 16;   // B-stage: 128 rows x 2 halves

    f32x4 acc[4][4];
#pragma unroll
    for (int mt = 0; mt < 4; mt++)
#pragma unroll
        for (int nt = 0; nt < 4; nt++) acc[mt][nt] = (f32x4){0.f, 0.f, 0.f, 0.f};

    for (int k0 = 0; k0 < 64; k0 += 32) {
        *(short8*)&As[r1][o1] = *(const short8*)(Abase + (size_t)r1 * HD + k0 + o1);
        *(short8*)&As[r2][o2] = *(const short8*)(Abase + (size_t)r2 * HD + k0 + o2);
        // Bs[c][kk] = Wk[h*64+k0+kk][col0+c] = WkT[col0+c][h*64+k0+kk]
        {
            const ushort* wsrc = WkT + (size_t)(col0 + r1b) * 1024 + h * HD + k0 + o1b;
            *(short8*)&Bs[r1b][o1b]     = *(const short8*)wsrc;
            *(short8*)&Bs[r1b][o1b + 8] = *(const short8*)(wsrc + 8);
        }
        __syncthreads();
        short8 af[4], bf[4];
#pragma unroll
        for (int mt = 0; mt < 4; mt++) af[mt] = *(const short8*)&As[wr + mt * 16 + n][qd * 8];
#pragma unroll
        for (int nt = 0; nt < 4; nt++) bf[nt] = *(const short8*)&Bs[wc + nt * 16 + n][qd * 8];
#pragma unroll
        for (int mt = 0; mt < 4; mt++)
#pragma unroll
            for (int nt = 0; nt < 4; nt++)
                acc[mt][nt] = __builtin_amdgcn_mfma_f32_16x16x32_bf16(af[mt], bf[nt], acc[mt][nt], 0, 0, 0);
        __syncthreads();
    }
#pragma unroll
    for (int mt = 0; mt < 4; mt++)
#pragma unroll
        for (int nt = 0; nt < 4; nt++)
#pragma unroll
            for (int r = 0; r < 4; r++) {
                int token = row0 + wr + mt * 16 + qd * 4 + r;
                int col = col0 + wc + nt * 16 + n;
                qproj[((size_t)token * NH + h) * 1024 + col] = f2bf(acc[mt][nt][r]);
            }
}

// vproj per head: merged[t, h*64+d] += wvec_h[t,:]·Wv[h*64+d,:] + wsum*bv (in-place bf16)
__global__ __launch_bounds__(256) void mfma_vproj_kernel(
    const ushort* __restrict__ wvecb, const ushort* __restrict__ Wvb,
    const float* __restrict__ bv, const float* __restrict__ wmem,
    ushort* __restrict__ mergedb)
{
    __shared__ ushort As[128][40];
    __shared__ ushort Bs[64][40];
    const int tid = threadIdx.x;
    const int w = tid >> 6, lane = tid & 63;
    const int n = lane & 15, qd = lane >> 4;
    const int wr = (w >> 1) * 64, wc = (w & 1) * 32;
    const int row0 = blockIdx.x * 128;
    const int h = blockIdx.y;
    const int r1 = tid >> 2, o1 = (tid & 3) * 8;
    const int r2 = (tid + 256) >> 2, o2 = ((tid + 256) & 3) * 8;

    f32x4 acc[4][2];
#pragma unroll
    for (int mt = 0; mt < 4; mt++)
#pragma unroll
        for (int nt = 0; nt < 2; nt++) acc[mt][nt] = (f32x4){0.f, 0.f, 0.f, 0.f};

    for (int k0 = 0; k0 < 1024; k0 += 32) {
        *(short8*)&As[r1][o1] = *(const short8*)(wvecb + ((size_t)(row0 + r1) * NH + h) * 1024 + k0 + o1);
        *(short8*)&As[r2][o2] = *(const short8*)(wvecb + ((size_t)(row0 + r2) * NH + h) * 1024 + k0 + o2);
        *(short8*)&Bs[r1 & 63][o1] = *(const short8*)(Wvb + (size_t)(h * HD + (r1 & 63)) * 1024 + k0 + o1);
        __syncthreads();
        short8 af[4], bf[2];
#pragma unroll
        for (int mt = 0; mt < 4; mt++) af[mt] = *(const short8*)&As[wr + mt * 16 + n][qd * 8];
#pragma unroll
        for (int nt = 0; nt < 2; nt++) bf[nt] = *(const short8*)&Bs[wc + nt * 16 + n][qd * 8];
#pragma unroll
        for (int mt = 0; mt < 4; mt++)
#pragma unroll
            for (int nt = 0; nt < 2; nt++)
                acc[mt][nt] = __builtin_amdgcn_mfma_f32_16x16x32_bf16(af[mt], bf[nt], acc[mt][nt], 0, 0, 0);
        __syncthreads();
    }
#pragma unroll
    for (int mt = 0; mt < 4; mt++)
#pragma unroll
        for (int nt = 0; nt < 2; nt++)
#pragma unroll
            for (int r = 0; r < 4; r++) {
                int token = row0 + wr + mt * 16 + qd * 4 + r;
                int d = wc + nt * 16 + n;
                float ws = wmem[((size_t)token * NH + h) * 16 + 12];
                size_t mi = (size_t)token * DIM + h * HD + d;
                float val = bf2f(mergedb[mi]) + acc[mt][nt][r] + ws * bv[h * HD + d];
                mergedb[mi] = f2bf(val);
            }
}

// mem_scores fused: per token, D[h][m] = qproj_h · mem_m via one MFMA chain.
__global__ __launch_bounds__(256) void msc_fused_kernel(
    const ushort* __restrict__ qproj, const ushort* __restrict__ mem_n,
    const ushort* __restrict__ qkvb, const float* __restrict__ bqkv,
    float* __restrict__ msc)
{
    const int tid = threadIdx.x;
    const int w = tid >> 6, lane = tid & 63;
    const int n = lane & 15, qd = lane >> 4;
    const int bs = blockIdx.x * 4 + w;

    float qbk = 0.f;
    if (lane < 16) {
        int b = bs >> 10, s = bs & 1023;
        const ushort* qrow = qkvb + ((size_t)(b * NH + lane) * SEQ + s) * HD;
        const float* bk = bqkv + DIM + lane * HD;
#pragma unroll
        for (int d = 0; d < HD; d++) qbk += bf2f(qrow[d]) * bk[d];
    }
    f32x4 acc = (f32x4){0.f, 0.f, 0.f, 0.f};
    const ushort* qpB = qproj + ((size_t)bs * NH + n) * 1024;
    const int mrow = (n < NM) ? n : 0;
    const ushort* mmB = mem_n + ((size_t)bs * NM + mrow) * 1024;
    for (int k0 = 0; k0 < 1024; k0 += 32) {
        short8 af = *(const short8*)(qpB + k0 + qd * 8);
        short8 bf = *(const short8*)(mmB + k0 + qd * 8);
        acc = __builtin_amdgcn_mfma_f32_16x16x32_bf16(af, bf, acc, 0, 0, 0);
    }
#pragma unroll
    for (int r = 0; r < 4; r++) {
        int h = qd * 4 + r;
        float qb = __shfl(qbk, h);
        if (n < NM)
            msc[((size_t)bs * NH + h) * NM + n] = 0.125f * (acc[r] + qb);
    }
}

// ---------------------------------------------------------------------------
// Flash attention (MFMA bf16), 8-wave split-KV.
// ---------------------------------------------------------------------------
#define TQ 64
#define TK 64
__global__ __launch_bounds__(512) void flash_attn_kernel(
    const ushort* __restrict__ qkvb, const float* __restrict__ msc,
    ushort* __restrict__ mergedb, float* __restrict__ wmem)
{
    // 55296 B total: Ks[2][64][72] | Vt[2][64][72] | Ps[8][16][72]
    // cbuf (combine, 4x64x25 f32 = 25600 B) aliases Ks/Vt after the KV loop.
    __shared__ __align__(16) char smem[55296];
    ushort (*Ks)[TK][72]  = (ushort (*)[TK][72])smem;
    ushort (*Vt)[HD][72]  = (ushort (*)[HD][72])(smem + 18432);
    ushort (*Ps)[16][72]  = (ushort (*)[16][72])(smem + 36864);
    float  (*cbuf)[64][25] = (float (*)[64][25])smem;

    const int bxr = blockIdx.x;
    const int qt = (bxr & 1) ? (bxr >> 1) : (15 - (bxr >> 1));
    const int bh = blockIdx.y;
    const int b = bh >> 4, h = bh & 15;
    const int tid = threadIdx.x;
    const int w = tid >> 6;        // 0..7
    const int g = w >> 2;          // kv parity group
    const int wq = w & 3;          // q sub-tile within the 64-row block
    const int lane = tid & 63;
    const int n = lane & 15;
    const int qd = lane >> 4;

    const ushort* qb = qkvb;
    const ushort* kb = qkvb + (size_t)OUTT;
    const ushort* vb = qkvb + (size_t)2 * OUTT;
    const size_t headoff = (size_t)bh * SEQ * HD;

    const int qrow0 = qt * TQ + wq * 16;
    const ushort* qp = qb + headoff + (size_t)(qrow0 + n) * HD;
    short8 qf0 = *(const short8*)(qp + qd * 8);
    short8 qf1 = *(const short8*)(qp + 32 + qd * 8);

    float mrow[4], lrow[4];
    f32x4 Oacc[4];
#pragma unroll
    for (int r = 0; r < 4; r++) { mrow[r] = NEGBIG; lrow[r] = 0.f; }
#pragma unroll
    for (int nt = 0; nt < 4; nt++) Oacc[nt] = (f32x4){0.f, 0.f, 0.f, 0.f};

    // staging indices within each 256-thread group
    const int gtid = tid & 255;
    const int key = gtid >> 2;
    const int c0 = (gtid & 3) * 16;
    const int nsteps = (qt + 2) >> 1;   // ceil((qt+1)/2)

    for (int step = 0; step < nsteps; ++step) {
        const int kt = 2 * step + g;
        const bool act = (kt <= qt);
        if (act) {
            const ushort* kg = kb + headoff + (size_t)(kt * TK + key) * HD + c0;
            *(short8*)&Ks[g][key][c0]     = *(const short8*)kg;
            *(short8*)&Ks[g][key][c0 + 8] = *(const short8*)(kg + 8);
            const ushort* vg = vb + headoff + (size_t)(kt * TK + key) * HD + c0;
            ushort vs[16];
            *(short8*)&vs[0] = *(const short8*)vg;
            *(short8*)&vs[8] = *(const short8*)(vg + 8);
#pragma unroll
            for (int i = 0; i < 16; i++) Vt[g][c0 + i][key] = vs[i];
        }
        __syncthreads();
        if (act) {
            f32x4 sacc[4];
#pragma unroll
            for (int kc = 0; kc < 4; kc++) {
                short8 kf0 = *(const short8*)&Ks[g][kc * 16 + n][qd * 8];
                short8 kf1 = *(const short8*)&Ks[g][kc * 16 + n][32 + qd * 8];
                f32x4 z = (f32x4){0.f, 0.f, 0.f, 0.f};
                z = __builtin_amdgcn_mfma_f32_16x16x32_bf16(qf0, kf0, z, 0, 0, 0);
                z = __builtin_amdgcn_mfma_f32_16x16x32_bf16(qf1, kf1, z, 0, 0, 0);
                sacc[kc] = z;
            }
            const bool diag = (kt == qt);
#pragma unroll
            for (int kc = 0; kc < 4; kc++) {
#pragma unroll
                for (int r = 0; r < 4; r++) {
                    float sv = sacc[kc][r] * 0.125f;
                    if (diag) {
                        int qrow = qrow0 + qd * 4 + r;
                        int kk = kt * TK + kc * 16 + n;
                        if (kk > qrow) sv = NEGBIG;
                    }
                    sacc[kc][r] = sv;
                }
            }
            float alpha[4];
#pragma unroll
            for (int r = 0; r < 4; r++) {
                float mx = fmaxf(fmaxf(sacc[0][r], sacc[1][r]), fmaxf(sacc[2][r], sacc[3][r]));
                mx = fmaxf(mx, __shfl_xor(mx, 1));
                mx = fmaxf(mx, __shfl_xor(mx, 2));
                mx = fmaxf(mx, __shfl_xor(mx, 4));
                mx = fmaxf(mx, __shfl_xor(mx, 8));
                float mnew = fmaxf(mrow[r], mx);
                alpha[r] = __expf(mrow[r] - mnew);
                mrow[r] = mnew;
            }
            float psum[4] = {0.f, 0.f, 0.f, 0.f};
#pragma unroll
            for (int kc = 0; kc < 4; kc++) {
#pragma unroll
                for (int r = 0; r < 4; r++) {
                    float p = __expf(sacc[kc][r] - mrow[r]);
                    psum[r] += p;
                    Ps[w][qd * 4 + r][kc * 16 + n] = f2bf(p);
                }
            }
#pragma unroll
            for (int r = 0; r < 4; r++) {
                float ps = psum[r];
                ps += __shfl_xor(ps, 1);
                ps += __shfl_xor(ps, 2);
                ps += __shfl_xor(ps, 4);
                ps += __shfl_xor(ps, 8);
                lrow[r] = alpha[r] * lrow[r] + ps;
            }
#pragma unroll
            for (int nt = 0; nt < 4; nt++)
#pragma unroll
                for (int r = 0; r < 4; r++)
                    Oacc[nt][r] *= alpha[r];
            short8 pf0 = *(const short8*)&Ps[w][n][qd * 8];
            short8 pf1 = *(const short8*)&Ps[w][n][32 + qd * 8];
#pragma unroll
            for (int nt = 0; nt < 4; nt++) {
                short8 vf0 = *(const short8*)&Vt[g][nt * 16 + n][qd * 8];
                short8 vf1 = *(const short8*)&Vt[g][nt * 16 + n][32 + qd * 8];
                f32x4 z = Oacc[nt];
                z = __builtin_amdgcn_mfma_f32_16x16x32_bf16(pf0, vf0, z, 0, 0, 0);
                z = __builtin_amdgcn_mfma_f32_16x16x32_bf16(pf1, vf1, z, 0, 0, 0);
                Oacc[nt] = z;
            }
        }
        __syncthreads();
    }

    // --- two-way combine: group 1 hands its state to group 0 via LDS ---
    if (g == 1) {
        float* cb = cbuf[wq][lane];
#pragma unroll
        for (int nt = 0; nt < 4; nt++)
#pragma unroll
            for (int r = 0; r < 4; r++) cb[nt * 4 + r] = Oacc[nt][r];
#pragma unroll
        for (int r = 0; r < 4; r++) { cb[16 + r] = mrow[r]; cb[20 + r] = lrow[r]; }
    }
    __syncthreads();
    if (g == 1) return;

    {
        const float* cb = cbuf[wq][lane];
#pragma unroll
        for (int r = 0; r < 4; r++) {
            float m1 = cb[16 + r], l1 = cb[20 + r];
            float mnew = fmaxf(mrow[r], m1);
            float a0 = __expf(mrow[r] - mnew);
            float a1 = __expf(m1 - mnew);
            lrow[r] = a0 * lrow[r] + a1 * l1;
#pragma unroll
            for (int nt = 0; nt < 4; nt++)
                Oacc[nt][r] = a0 * Oacc[nt][r] + a1 * cb[nt * 4 + r];
            mrow[r] = mnew;
        }
    }

#pragma unroll
    for (int r = 0; r < 4; r++) {
        int srow = qrow0 + qd * 4 + r;
        const float* mp = msc + ((size_t)(b * SEQ + srow) * NH + h) * NM;
        float mm = NEGBIG;
#pragma unroll
        for (int j = 0; j < NM; j++) mm = fmaxf(mm, mp[j]);
        float mf = fmaxf(mrow[r], mm);
        float al = __expf(mrow[r] - mf);
        float msum = 0.f;
#pragma unroll
        for (int j = 0; j < NM; j++) msum += __expf(mp[j] - mf);
        float lf = al * lrow[r] + msum;
        float inv = 1.f / lf;
        float scale = al * inv;
        ushort* mrow_out = mergedb + (size_t)(b * SEQ + srow) * DIM + h * HD;
#pragma unroll
        for (int nt = 0; nt < 4; nt++)
            mrow_out[nt * 16 + n] = f2bf(Oacc[nt][r] * scale);
        size_t wb = ((size_t)(b * SEQ + srow) * NH + h) * 16;
        if (n < 12)       wmem[wb + n]  = __expf(mp[n] - mf) * inv;
        else if (n == 12) wmem[wb + 12] = msum * inv;
    }
}

// ---------------------------------------------------------------------------
// wvec[bs,h,:] = sum_m wmem[bs,h,m] * mem_n[bs,m,:]  (bf16 out)
// ---------------------------------------------------------------------------
__global__ __launch_bounds__(256) void wvec_kernel(
    const float* __restrict__ wmem, const ushort* __restrict__ mem_n,
    ushort* __restrict__ wvecb)
{
    __shared__ ushort memL[NM][1032];
    __shared__ float wL[NH][NM];
    const int bs = blockIdx.x;
    const int tid = threadIdx.x;

    for (int t = tid; t < NM * 256; t += 256) {
        int m = t >> 8, c4 = (t & 255) << 2;
        *(ushort4*)&memL[m][c4] = *(const ushort4*)(mem_n + ((size_t)bs * NM + m) * 1024 + c4);
    }
    if (tid < NH * NM) {
        int h = tid / NM, m = tid % NM;
        wL[h][m] = wmem[((size_t)bs * NH + h) * 16 + m];
    }
    __syncthreads();

    for (int h = 0; h < NH; h++) {
#pragma unroll
        for (int c0 = 0; c0 < 1024; c0 += 256) {
            int c = c0 + tid;
            float acc = 0.f;
#pragma unroll
            for (int m = 0; m < NM; m++)
                acc = fmaf(wL[h][m], bf2f(memL[m][c]), acc);
            wvecb[((size_t)bs * NH + h) * 1024 + c] = f2bf(acc);
        }
    }
}

// ---------------------------------------------------------------------------
extern "C" void kernel_launch(void* const* d_in, const int* in_sizes, int n_in,
                              void* d_out, int out_size, void* d_ws, size_t ws_size,
                              hipStream_t stream) {
    const float* x    = (const float*)d_in[0];
    const float* pk   = (const float*)d_in[1];
    const float* pv   = (const float*)d_in[2];
    const float* pq   = (const float*)d_in[3];
    const float* Wqkv = (const float*)d_in[4];
    const float* bqkv = (const float*)d_in[5];
    const float* Wout = (const float*)d_in[6];
    const float* bout = (const float*)d_in[7];
    float* out = (float*)d_out;

    // ws: mem_n 50.3 | qproj/wvecb 67.1 (aliased) | msc 1.6 | wmem 2.1 |
    //     qkvb 12.6 | Wqkvb 6.3 | Woutb 2.1 | xb/mergedb 4.2 (aliased) |
    //     WkT 2.1  ~148 MB
    ushort* mem_n  = (ushort*)d_ws;
    ushort* qproj  = mem_n + (size_t)MEMROWS * 1024;
    ushort* wvecb  = qproj;                                 // alias: qproj dead after msc
    float*  msc    = (float*)(qproj + (size_t)NTOK * NH * 1024);
    float*  wmem   = msc + (size_t)NTOK * NH * NM;
    ushort* qkvb   = (ushort*)(wmem + (size_t)NTOK * NH * 16);
    ushort* Wqkvb  = qkvb + (size_t)3 * OUTT;
    ushort* Woutb  = Wqkvb + (size_t)3072 * 1024;
    ushort* xb     = Woutb + (size_t)1024 * 1024;
    ushort* mergedb = xb;                                   // alias: xb dead after qkv gemm
    ushort* WkT    = xb + (size_t)NTOK * 1024;              // 2 MB, after xb region

    const int na4 = NTOK * DIM / 4, nb4 = 3 * DIM * DIM / 4, nc4 = DIM * DIM / 4;

    // 1. bf16 conversions
    cvt3_kernel<<<(na4 + nb4 + nc4 + 255) / 256, 256, 0, stream>>>(
        x, xb, na4, Wqkv, Wqkvb, nb4, Wout, Woutb, nc4);
    // 1b. Wk transpose (one-time ~3us) -> WkT for qproj staging
    transpose_wk_kernel<<<256, 256, 0, stream>>>(Wqkvb + (size_t)DIM * DIM, WkT);
    // 2+3. FUSED: qkv GEMM (384 blocks) + layernorm of mem rows (6144 blocks).
    qkv_ln_fused_kernel<<<QKV_BLKS + MEMROWS / 4, 256, 0, stream>>>(
        xb, Wqkvb, bqkv, out, qkvb, pq, pk, pv, mem_n);
    // 4. qproj (MFMA, per head) — B staged from WkT, vectorized LDS writes
    mfma_qproj_kernel<<<dim3(8, 16, NH), 256, 0, stream>>>(qkvb, WkT, qproj);
    // 5. mem scores (fused MFMA per token)
    msc_fused_kernel<<<NTOK / 4, 256, 0, stream>>>(qproj, mem_n, qkvb, bqkv, msc);
    // 6. flash attention (8-wave split-KV) -> mergedb bf16, wmem
    flash_attn_kernel<<<dim3(16, 32), 512, 0, stream>>>(qkvb, msc, mergedb, wmem);
    // 7. wvec
    wvec_kernel<<<NTOK, 256, 0, stream>>>(wmem, mem_n, wvecb);
    // 8. vproj (MFMA, per head): mergedb += wvec@Wv^T + wsum*bv (in place)
    mfma_vproj_kernel<<<dim3(16, NH), 256, 0, stream>>>(
        wvecb, Wqkvb + (size_t)2 * DIM * DIM, bqkv + 2 * DIM, wmem, mergedb);
    // 9. out GEMM (MFMA) -> d_out fp32
    mfma_out_kernel<<<dim3(8, 16), 256, 0, stream>>>(mergedb, Woutb, bout, out);
}